// Round 10
// baseline (311.977 us; speedup 1.0000x reference)
//
#include <hip/hip_runtime.h>

#define NNODE 50000
#define NEDGE 600000
#define KDIN  239
#define DDIM  128
#define NTILES 3125           // 3125*16 == 50000 exactly
#define NBG   782             // one-shot gemm blocks: 782*4 waves >= 3125 tiles

typedef _Float16 half8 __attribute__((ext_vector_type(8)));
typedef _Float16 half4 __attribute__((ext_vector_type(4)));
typedef __attribute__((ext_vector_type(4))) float f32x4;

__device__ __forceinline__ ushort f2h(float f){
  union { _Float16 h; ushort u; } c; c.h = (_Float16)f; return c.u;
}
// monotone float<->uint encoding for atomicMax on signed floats
__device__ __forceinline__ unsigned fenc(float f){
  union { float f; unsigned u; } v; v.f = f;
  return (v.u & 0x80000000u) ? ~v.u : (v.u | 0x80000000u);
}
__device__ __forceinline__ float fdec(unsigned k){
  union { unsigned u; float f; } v;
  v.u = (k & 0x80000000u) ? (k & 0x7FFFFFFFu) : ~k;
  return v.f;
}

// ---- prologue: weight transposes -> f16 [n][Kpad]  ||  degree count ----
__global__ __launch_bounds__(256) void pre_k(
    const float* __restrict__ W_in, const float* __restrict__ W_gat, const float* __restrict__ W_h,
    ushort* __restrict__ BfA, ushort* __restrict__ BfB, ushort* __restrict__ BfC,
    const int* __restrict__ ei, int* __restrict__ cnt)
{
  const int b = blockIdx.x, t = threadIdx.x;
  if (b < 128){                                    // W_in [239,128] -> BfA[n=128][k=256]
    int idx = b*256 + t; int n = idx >> 8, k = idx & 255;
    BfA[idx] = (k < KDIN) ? f2h(W_in[(size_t)k*DDIM + n]) : (ushort)0;
  } else if (b < 192){                             // W_gat -> BfB[n][128]
    int idx = (b-128)*256 + t; int n = idx >> 7, k = idx & 127;
    BfB[idx] = f2h(W_gat[(size_t)k*DDIM + n]);
  } else if (b < 256){                             // W_h -> BfC[n][128]
    int idx = (b-192)*256 + t; int n = idx >> 7, k = idx & 127;
    BfC[idx] = f2h(W_h[(size_t)k*DDIM + n]);
  } else {                                         // degree count (cnt pre-zeroed)
    int e = (b-256)*256 + t;
    if (e < NEDGE){
      int dst = min(max(ei[NEDGE + e], 0), NNODE-1);
      atomicAdd(&cnt[dst], 1);
    }
  }
}

// ---- one-shot MFMA GEMM: each wave computes ONE 16x128 tile, then exits ----
// AMODE 0: A = raw fp32 [M,239] (gemmA);  AMODE 1: A = f16 [M,128]
// EPI 0: leaky(.01)(v+bias) -> f16
// EPI 1: v -> f16 g + row dots os/od (att_src/att_dst) + global max -> gm[0..1]
// EPI 2: h2=leaky(.01)(v+bias); y = h2@W_out + b_out -> outf fp32
// XW 1: extra blocks run prefix-scan of degrees; XW 2: extra blocks run CSR scatter
template<int KSTEPS, int EPI, int XW, int AMODE>
__global__ __launch_bounds__(256, 4) void gemm5_k(
    const float* __restrict__ Afp, const ushort* __restrict__ Af,
    const ushort* __restrict__ Btf, const float* __restrict__ bias,
    float* __restrict__ outf, ushort* __restrict__ outh,
    const float* __restrict__ vs, const float* __restrict__ vd,
    float* __restrict__ os, float* __restrict__ od, unsigned* __restrict__ gm,
    const int* __restrict__ ei, int* __restrict__ cnt, int* __restrict__ cursor,
    int* __restrict__ es)
{
  constexpr int Kpad = KSTEPS*32;
  if (XW == 1 && blockIdx.x >= NBG){               // prefix-scan of degrees
    __shared__ int wtot[4];
    __shared__ int bbase;
    const int lane = threadIdx.x & 63, wave = threadIdx.x >> 6;
    const int node = (blockIdx.x - NBG)*256 + threadIdx.x;
    const int mycnt = (node < NNODE) ? cnt[node] : 0;
    int val = mycnt;
    #pragma unroll
    for (int d=1; d<64; d<<=1){ int tv = __shfl_up(val, d); if (lane >= d) val += tv; }
    if (lane == 63) wtot[wave] = val;
    __syncthreads();
    if (threadIdx.x == 0){
      int run = 0;
      #pragma unroll
      for (int i=0;i<4;i++){ int tv = wtot[i]; wtot[i] = run; run += tv; }
      bbase = (int)atomicAdd(&gm[2], (unsigned)run);
    }
    __syncthreads();
    if (node < NNODE){
      const int off = bbase + wtot[wave] + val - mycnt;
      cnt[node] = off; cursor[node] = off;
    }
    return;
  }
  if (XW == 2 && blockIdx.x >= NBG){               // CSR scatter (src only)
    int e = (blockIdx.x - NBG)*256 + threadIdx.x;
    if (e < NEDGE){
      int src = min(max(ei[e], 0), NNODE-1);
      int dst = min(max(ei[NEDGE + e], 0), NNODE-1);
      int pos = atomicAdd(&cursor[dst], 1);
      es[pos] = src;
    }
    return;
  }
  const int lane = threadIdx.x & 63;
  const int wave = threadIdx.x >> 6;
  const int q = lane >> 4, c = lane & 15;
  const int tile = blockIdx.x*4 + wave;
  if (tile >= NTILES) return;
  const int rowBase = tile*16;
  const int arow = rowBase + c;                    // always < NNODE (3125*16 exact)
  // A fragments for this tile (KSTEPS independent 16B loads, or scalar fp32+cvt)
  half8 af[KSTEPS];
  if (AMODE == 0){
    const float* __restrict__ ap = Afp + (size_t)arow*KDIN;
    #pragma unroll
    for (int s=0;s<KSTEPS;s++){
      #pragma unroll
      for (int i=0;i<8;i++){
        const int k = s*32 + q*8 + i;
        af[s][i] = (_Float16)((k < KDIN) ? ap[k] : 0.f);
      }
    }
  } else {
    const ushort* __restrict__ ap = Af + (size_t)arow*Kpad + q*8;
    #pragma unroll
    for (int s=0;s<KSTEPS;s++) af[s] = *(const half8*)(ap + s*32);
  }
  f32x4 acc[8];
  #pragma unroll
  for (int t=0;t<8;t++) acc[t] = (f32x4){0.f,0.f,0.f,0.f};
  // single-use B fragments straight from L2-hot global (no residency pressure)
  #pragma unroll
  for (int s=0;s<KSTEPS;s++){
    #pragma unroll
    for (int t=0;t<8;t++){
      const half8 bf = *(const half8*)(Btf + (size_t)(16*t + c)*Kpad + s*32 + q*8);
      acc[t] = __builtin_amdgcn_mfma_f32_16x16x32_f16(af[s], bf, acc[t], 0,0,0);
    }
  }
  // epilogue: C/D layout col=lane&15, row=(lane>>4)*4+reg  [m89/m91-verified]
  float pr0[4] = {0,0,0,0}, pr1[4] = {0,0,0,0};
  #pragma unroll
  for (int t=0;t<8;t++){
    const int col = 16*t + c;
    const float bv = (EPI != 1) ? bias[col] : 0.f;
    float va=0.f, vb=0.f;
    if (EPI == 1){ va = vs[col]; vb = vd[col]; }
    if (EPI == 2){ va = vs[2*col]; vb = vs[2*col+1]; }
    #pragma unroll
    for (int r=0;r<4;r++){
      const int row = rowBase + q*4 + r;
      float v = acc[t][r] + bv;
      if (EPI != 1) v = (v >= 0.f) ? v : 0.01f*v;
      if (EPI == 0){
        outh[(size_t)row*DDIM + col] = f2h(v);
      } else if (EPI == 1){
        outh[(size_t)row*DDIM + col] = f2h(v);
        pr0[r] += v*va; pr1[r] += v*vb;
      } else {
        pr0[r] += v*va; pr1[r] += v*vb;
      }
    }
  }
  if (EPI >= 1){
    float lmax_s = -3.0e38f, lmax_d = -3.0e38f;
    #pragma unroll
    for (int r=0;r<4;r++){
      float s0 = pr0[r], s1 = pr1[r];
      s0 += __shfl_xor(s0,8); s1 += __shfl_xor(s1,8);
      s0 += __shfl_xor(s0,4); s1 += __shfl_xor(s1,4);
      s0 += __shfl_xor(s0,2); s1 += __shfl_xor(s1,2);
      s0 += __shfl_xor(s0,1); s1 += __shfl_xor(s1,1);
      if (EPI == 1){ lmax_s = fmaxf(lmax_s, s0); lmax_d = fmaxf(lmax_d, s1); }
      if (c == 0){
        const int row = rowBase + q*4 + r;
        if (EPI == 1){ os[row] = s0; od[row] = s1; }
        else { float2 y2; y2.x = s0 + vd[0]; y2.y = s1 + vd[1];
               *(float2*)&outf[(size_t)row*2] = y2; }
      }
    }
    if (EPI == 1){
      #pragma unroll
      for (int off=32; off>0; off>>=1){
        lmax_s = fmaxf(lmax_s, __shfl_xor(lmax_s, off));
        lmax_d = fmaxf(lmax_d, __shfl_xor(lmax_d, off));
      }
      if (lane == 0){ atomicMax(&gm[0], fenc(lmax_s)); atomicMax(&gm[1], fenc(lmax_d)); }
    }
  }
}

// ---- fused softmax+gather: og[dst] = softmax-agg(g f16) + b_gat -> f16 ----
// Each HALF-WAVE (32 lanes) owns ONE dst and processes it INDEPENDENTLY
// (j from 0, unconditional self-loop, own write) — R8-proven scheme.
// 4 independent gather streams for MLP. Global shift M (upper bound on e).
__global__ __launch_bounds__(256) void agg_k(const ushort* __restrict__ gf,
    const int* __restrict__ offs, const int* __restrict__ cur,
    const int* __restrict__ es,
    const float* __restrict__ a_src, const float* __restrict__ a_dst,
    const unsigned* __restrict__ gm, const float* __restrict__ b_gat,
    ushort* __restrict__ og)
{
  const int lane = threadIdx.x & 63;
  const int half = lane >> 5, li = lane & 31;
  const int dst = blockIdx.x*8 + (threadIdx.x >> 6)*2 + half;
  if (dst >= NNODE) return;
  float M = fdec(gm[0]) + fdec(gm[1]);
  M = (M >= 0.f) ? M : 0.2f*M;
  const int start = offs[dst];
  const int deg = cur[dst] - start;
  const int* __restrict__ bin = es + start;
  const float ad = a_dst[dst];
  f32x4 a0={0,0,0,0}, a1={0,0,0,0}, a2={0,0,0,0}, a3={0,0,0,0};
  float w0s=0.f, w1s=0.f, w2s=0.f, w3s=0.f;
  int j = 0;
  for (; j+3 < deg; j += 4){                       // 4 gather streams in flight
    const int i0=bin[j], i1=bin[j+1], i2=bin[j+2], i3=bin[j+3];
    float e0=a_src[i0]+ad; e0=(e0>=0.f)?e0:0.2f*e0;
    float e1=a_src[i1]+ad; e1=(e1>=0.f)?e1:0.2f*e1;
    float e2=a_src[i2]+ad; e2=(e2>=0.f)?e2:0.2f*e2;
    float e3=a_src[i3]+ad; e3=(e3>=0.f)?e3:0.2f*e3;
    const float w0=__expf(e0-M), w1=__expf(e1-M), w2=__expf(e2-M), w3=__expf(e3-M);
    const half4 g0 = *(const half4*)(gf + (size_t)i0*DDIM + li*4);
    const half4 g1 = *(const half4*)(gf + (size_t)i1*DDIM + li*4);
    const half4 g2 = *(const half4*)(gf + (size_t)i2*DDIM + li*4);
    const half4 g3 = *(const half4*)(gf + (size_t)i3*DDIM + li*4);
    #pragma unroll
    for (int i=0;i<4;i++){
      a0[i] += w0*(float)g0[i]; a1[i] += w1*(float)g1[i];
      a2[i] += w2*(float)g2[i]; a3[i] += w3*(float)g3[i];
    }
    w0s += w0; w1s += w1; w2s += w2; w3s += w3;
  }
  for (; j < deg; ++j){
    const int si = bin[j];
    float e0=a_src[si]+ad; e0=(e0>=0.f)?e0:0.2f*e0;
    const float w = __expf(e0-M);
    const half4 gv = *(const half4*)(gf + (size_t)si*DDIM + li*4);
    #pragma unroll
    for (int i=0;i<4;i++) a0[i] += w*(float)gv[i];
    w0s += w;
  }
  {                                                // self-loop (unconditional)
    float evs=a_src[dst]+ad; evs=(evs>=0.f)?evs:0.2f*evs;
    const float w = __expf(evs-M);
    const half4 gv = *(const half4*)(gf + (size_t)dst*DDIM + li*4);
    #pragma unroll
    for (int i=0;i<4;i++) a0[i] += w*(float)gv[i];
    w0s += w;
  }
  const float inv = 1.f/(w0s+w1s+w2s+w3s);         // >= w_self > 0
  const float4 bg = *(const float4*)&b_gat[li*4];
  ushort4 o;
  o.x = f2h((a0[0]+a1[0]+a2[0]+a3[0])*inv + bg.x);
  o.y = f2h((a0[1]+a1[1]+a2[1]+a3[1])*inv + bg.y);
  o.z = f2h((a0[2]+a1[2]+a2[2]+a3[2])*inv + bg.z);
  o.w = f2h((a0[3]+a1[3]+a2[3]+a3[3])*inv + bg.w);
  *(ushort4*)(og + (size_t)dst*DDIM + li*4) = o;
}

extern "C" void kernel_launch(void* const* d_in, const int* in_sizes, int n_in,
                              void* d_out, int out_size, void* d_ws, size_t ws_size,
                              hipStream_t stream)
{
  const float* x       = (const float*)d_in[0];
  const int*   ei      = (const int*)d_in[1];
  // d_in[2] = edge_type (unused by reference)
  const float* W_in    = (const float*)d_in[3];
  const float* b_in    = (const float*)d_in[4];
  const float* W_gat   = (const float*)d_in[5];
  const float* att_src = (const float*)d_in[6];
  const float* att_dst = (const float*)d_in[7];
  const float* b_gat   = (const float*)d_in[8];
  const float* W_h     = (const float*)d_in[9];
  const float* b_h     = (const float*)d_in[10];
  const float* W_out   = (const float*)d_in[11];
  const float* b_out   = (const float*)d_in[12];

  // workspace (~42 MB, no aliasing):
  char* ws = (char*)d_ws;
  ushort*   hf     = (ushort*)  (ws + 0);          // h f16 [N,128]   12.8 MB
  ushort*   gf     = (ushort*)  (ws + 12800000);   // g f16 [N,128]   12.8 MB
  ushort*   og     = (ushort*)  (ws + 25600000);   // og f16 [N,128]  12.8 MB
  ushort*   BfA    = (ushort*)  (ws + 38400000);   // 64 KB
  ushort*   BfB    = (ushort*)  (ws + 38500000);   // 32 KB
  ushort*   BfC    = (ushort*)  (ws + 38600000);   // 32 KB
  int*      es     = (int*)     (ws + 38700000);   // CSR src, 2.4 MB
  int*      cnt    = (int*)     (ws + 41200000);   // 200 KB (then offsets)
  unsigned* gsmall = (unsigned*)(ws + 41400000);   // [gmax_s, gmax_d, gtotal]
  int*      cursor = (int*)     (ws + 41500000);   // 200 KB
  float*    a_src  = (float*)   (ws + 41700000);
  float*    a_dst  = (float*)   (ws + 41900000);

  hipMemsetAsync(cnt, 0, 200016, stream);          // cnt + gsmall (adjacent)

  // weights transpose/convert || degree count
  pre_k<<<256 + 2344, 256, 0, stream>>>(W_in, W_gat, W_h, BfA, BfB, BfC, ei, cnt);
  // gemmA: h = leaky(x@W_in + b_in) -> f16 (reads x fp32 directly)  || scan
  gemm5_k<8,0,1,0><<<NBG + 196, 256, 0, stream>>>(x, nullptr, BfA, b_in,
      nullptr, hf, nullptr, nullptr, nullptr, nullptr, gsmall, nullptr, cnt, cursor, nullptr);
  // gemmB: g = h@W_gat -> f16 + a_src/a_dst + global maxes  || CSR scatter
  gemm5_k<4,1,2,1><<<NBG + 2344, 256, 0, stream>>>(nullptr, hf, BfB, nullptr,
      nullptr, gf, att_src, att_dst, a_src, a_dst, gsmall, ei, cnt, cursor, es);
  // fused softmax + gather + normalize
  agg_k<<<6250, 256, 0, stream>>>(gf, cnt, cursor, es, a_src, a_dst, gsmall, b_gat, og);
  // gemmC: y = leaky(og@W_h + b_h) @ W_out + b_out -> d_out fp32
  gemm5_k<4,2,0,1><<<NBG, 256, 0, stream>>>(nullptr, og, BfC, b_h,
      (float*)d_out, nullptr, W_out, b_out, nullptr, nullptr, nullptr, nullptr, nullptr, nullptr, nullptr);
}